// Round 7
// baseline (2382.276 us; speedup 1.0000x reference)
//
#include <hip/hip_runtime.h>
#include <hip/hip_bf16.h>
#include <stdint.h>

#define NPT   16384   // N
#define BB    4
#define SS    1024    // NPOINT
#define KK    32      // NSAMPLE
#define RR    (BB*SS*KK) // 131072 rows
#define C1    67
#define O1    64
#define O3    128
#define EPSF  1e-5f
#define R2F   0.09f   // f32(0.09)
#define FT    1024    // FPS threads/block
#define FE    16      // FPS elements/thread

#define REP16(M) M(0) M(1) M(2) M(3) M(4) M(5) M(6) M(7) \
                 M(8) M(9) M(10) M(11) M(12) M(13) M(14) M(15)

// ---------------- FPS: one block/batch, x/y in LDS, z+dist in regs ------------
// Rounds 4-6 post-mortem: the register allocator refuses to keep ~64 loop-
// carried floats live across the 1024-iteration loop (VGPR stuck at 52-84,
// ~2000 cyc/iter of scratch reload traffic, L2-resident so invisible to
// FETCH_SIZE). Fix by construction: x,y planes live in LDS (128 KB float2,
// contiguous lane access = conflict-free ds_read_b64); only z+dist (32 named
// scalars, ~60 total demand) stay in registers -- a footprint the RA has
// granted in every previous round.
__global__ __launch_bounds__(FT)
__attribute__((amdgpu_waves_per_eu(4, 4)))
void k_fps(const float* __restrict__ xyz, int* __restrict__ fps_idx) {
    const int b = blockIdx.x;
    const int tid = threadIdx.x;
    const int lane = tid & 63, wv = tid >> 6;      // 16 waves
    const float* xb = xyz + (size_t)b * 3 * NPT;

    __shared__ float2 sxy[NPT];                    // 128 KB: (x,y) interleaved
    __shared__ uint2 s_red[2][16];

#define DECLV(i) float Z##i, D##i;
    REP16(DECLV)
#define INITV(i) { int n = (i) * FT + tid; \
                   float xx = xb[n]; \
                   float yy = xb[NPT + n]; \
                   float zz = xb[2 * NPT + n]; \
                   sxy[n] = make_float2(xx, yy); \
                   asm volatile("" : "+v"(zz)); \
                   Z##i = zz; D##i = 1e10f; }
    REP16(INITV)
    __syncthreads();                               // sxy visible to all waves

    int p = 0;
    int far = 0;
    float2 c0 = sxy[0];
    float cx = c0.x, cy = c0.y, cz = xb[2 * NPT];
    for (int it = 0; it < SS; ++it) {
        if (tid == 0) fps_idx[b * SS + it] = far;
        float bd = -1.0f; int bn = 0;
        // exact reference arithmetic: (dx*dx + dy*dy) + dz*dz, no FMA;
        // strict > keeps the lowest global index on ties (i ascending = n ascending)
#define UPDV(i) { float2 xy = sxy[(i) * FT + tid]; \
                  float dx = __fsub_rn(xy.x, cx); \
                  float dy = __fsub_rn(xy.y, cy); \
                  float dz = __fsub_rn(Z##i, cz); \
                  float d = __fadd_rn(__fadd_rn(__fmul_rn(dx, dx), __fmul_rn(dy, dy)), \
                                      __fmul_rn(dz, dz)); \
                  float dj = fminf(D##i, d); D##i = dj; \
                  bool gt = dj > bd; \
                  bd = gt ? dj : bd; \
                  bn = gt ? ((i) * FT + tid) : bn; }
        REP16(UPDV)

        // pack (dist, index): dist >= 0 so float bits compare monotonically.
        // ~n in low bits -> max key == max dist, ties -> smallest global index.
        unsigned long long key =
            ((unsigned long long)__float_as_uint(bd) << 32) | (unsigned)(~bn);
#pragma unroll
        for (int off = 32; off; off >>= 1) {
            unsigned long long ok = __shfl_xor(key, off);
            if (ok > key) key = ok;
        }
        if (lane == 0) s_red[p][wv] = make_uint2((unsigned)key, (unsigned)(key >> 32));
        __syncthreads();                  // single barrier per iteration
        // each wave merges the 16 partials: LDS broadcast read + 4-level shuffle
        uint2 e = s_red[p][lane & 15];
        unsigned long long k2 = ((unsigned long long)e.y << 32) | e.x;
#pragma unroll
        for (int off = 8; off; off >>= 1) {
            unsigned long long ok = __shfl_xor(k2, off);
            if (ok > k2) k2 = ok;
        }
        far = ~((unsigned)k2);            // all lanes converge to global max
        float2 cxy = sxy[far];            // uniform addr -> LDS broadcast
        cx = cxy.x; cy = cxy.y;
        cz = xb[2 * NPT + far];           // z plane from L2
        p ^= 1;                           // double buffer -> WAR-safe w/ 1 barrier
    }
#undef DECLV
#undef INITV
#undef UPDV
}

// ---------------- gather new_xyz: output0 (B,3,S) + ws copy (b,s,3) ------------
__global__ void k_newxyz(const float* __restrict__ xyz, const int* __restrict__ fps_idx,
                         float* __restrict__ out0, float* __restrict__ nxyz) {
    int g = blockIdx.x * blockDim.x + threadIdx.x;
    if (g >= BB * SS) return;
    int b = g / SS, s = g % SS;
    int id = fps_idx[g];
    const float* xb = xyz + (size_t)b * 3 * NPT;
#pragma unroll
    for (int c = 0; c < 3; ++c) {
        float v = xb[c * NPT + id];
        out0[(size_t)b * 3 * SS + c * SS + s] = v;
        nxyz[g * 3 + c] = v;
    }
}

// ---------------- ball query: one wave per centroid, ballot ranking ------------
__global__ __launch_bounds__(256) void k_ball(const float* __restrict__ xyz,
                                              const float* __restrict__ nxyz,
                                              int* __restrict__ ballidx) {
    int wid = (blockIdx.x * 256 + threadIdx.x) >> 6;   // 0..4095
    int lane = threadIdx.x & 63;
    int b = wid >> 10;
    const float* xb = xyz + (size_t)b * 3 * NPT;
    float nx = nxyz[wid * 3], ny = nxyz[wid * 3 + 1], nz = nxyz[wid * 3 + 2];
    int* out = ballidx + (size_t)wid * KK;
    int cnt = 0;
    int first = -1;
    for (int base = 0; base < NPT; base += 64) {
        int n = base + lane;
        float dx = __fsub_rn(nx, xb[n]);
        float dy = __fsub_rn(ny, xb[NPT + n]);
        float dz = __fsub_rn(nz, xb[2 * NPT + n]);
        float d = __fadd_rn(__fadd_rn(__fmul_rn(dx, dx), __fmul_rn(dy, dy)),
                            __fmul_rn(dz, dz));
        bool hit = !(d > R2F);            // excluded iff sqr > r^2 (matches ref)
        unsigned long long mask = __ballot(hit);
        if (mask) {
            if (first < 0) first = base + __builtin_ctzll(mask);
            int rank = cnt + __popcll(mask & ((1ull << lane) - 1ull));
            if (hit && rank < KK) out[rank] = n;
            cnt += __popcll(mask);
        }
        if (cnt >= KK) break;
    }
    if (lane >= cnt && lane < KK) out[lane] = first;   // pad with first hit
}

// ---------------- transpose pts (B,64,N) -> ptsT (B,N,64) ----------------------
__global__ __launch_bounds__(256) void k_tr(const float* __restrict__ pts,
                                            float* __restrict__ ptsT) {
    __shared__ float t[64][65];
    int b = blockIdx.x >> 8, n0 = (blockIdx.x & 255) << 6;
    const float* pb = pts + (size_t)b * 64 * NPT;
    int tx = threadIdx.x & 63, ty = threadIdx.x >> 6;  // ty in 0..3
#pragma unroll
    for (int k = 0; k < 16; ++k) {
        int c = ty * 16 + k;
        t[c][tx] = pb[(size_t)c * NPT + n0 + tx];      // coalesced in n
    }
    __syncthreads();
#pragma unroll
    for (int k = 0; k < 16; ++k) {
        int n = ty * 16 + k;
        ptsT[((size_t)b * NPT + n0 + n) * 64 + tx] = t[tx][n];  // coalesced in c
    }
}

// ---------------- layer1: gather + GEMM(67->64) + BN partial sums --------------
__global__ __launch_bounds__(256)
__attribute__((amdgpu_waves_per_eu(1, 4)))
void k_gemm1(const float* __restrict__ xyz,
        const float* __restrict__ ptsT, const float* __restrict__ nxyz,
        const int* __restrict__ ballidx, const float* __restrict__ w,
        const float* __restrict__ bias, float* __restrict__ Y,
        float* __restrict__ sumP, float* __restrict__ sqP) {
    __shared__ float wlds[C1 * O1];   // [c][o]
    __shared__ float blds[O1];
    __shared__ float lsum[4][O1];
    __shared__ float lsq[4][O1];
    for (int i = threadIdx.x; i < C1 * O1; i += 256) {
        int c = i >> 6, o = i & 63;
        wlds[i] = w[o * C1 + c];
    }
    if (threadIdx.x < O1) blds[threadIdx.x] = bias[threadIdx.x];
    __syncthreads();
    int r = blockIdx.x * 256 + threadIdx.x;
    int b = r >> 15;
    int g = r >> 5;
    int id = ballidx[r];
    const float* xb = xyz + (size_t)b * 3 * NPT;
    float acc[O1];
#pragma unroll
    for (int o = 0; o < O1; ++o) acc[o] = blds[o];
#pragma unroll
    for (int c = 0; c < 3; ++c) {
        float xv = xb[c * NPT + id] - nxyz[g * 3 + c];
        const float* wr = &wlds[c * O1];
#pragma unroll
        for (int o = 0; o < O1; ++o) acc[o] = fmaf(xv, wr[o], acc[o]);
    }
    const float4* p4 = (const float4*)(ptsT + ((size_t)b * NPT + id) * 64);
#pragma unroll 4
    for (int cc = 0; cc < 16; ++cc) {
        float4 x = p4[cc];
        float xs[4] = {x.x, x.y, x.z, x.w};
#pragma unroll
        for (int u = 0; u < 4; ++u) {
            const float* wr = &wlds[(3 + cc * 4 + u) * O1];
#pragma unroll
            for (int o = 0; o < O1; ++o) acc[o] = fmaf(xs[u], wr[o], acc[o]);
        }
    }
    float4* yr = (float4*)(Y + (size_t)r * O1);
#pragma unroll
    for (int o4 = 0; o4 < O1 / 4; ++o4)
        yr[o4] = make_float4(acc[o4 * 4], acc[o4 * 4 + 1], acc[o4 * 4 + 2], acc[o4 * 4 + 3]);
    int lane = threadIdx.x & 63, wvv = threadIdx.x >> 6;
#pragma unroll
    for (int o = 0; o < O1; ++o) {
        float v = acc[o], v2 = acc[o] * acc[o];
#pragma unroll
        for (int off = 1; off < 64; off <<= 1) { v += __shfl_xor(v, off); v2 += __shfl_xor(v2, off); }
        if (lane == 0) { lsum[wvv][o] = v; lsq[wvv][o] = v2; }
    }
    __syncthreads();
    if (threadIdx.x < O1) {
        int o = threadIdx.x;
        sumP[blockIdx.x * O1 + o] = lsum[0][o] + lsum[1][o] + lsum[2][o] + lsum[3][o];
        sqP[blockIdx.x * O1 + o]  = lsq[0][o] + lsq[1][o] + lsq[2][o] + lsq[3][o];
    }
}

// ---------------- generic MLP layer: 64 outputs PER BLOCK ----------------------
// OTOT total outputs; blockIdx.y selects which 64-wide half this block computes.
// NORM_IN applies relu(x*isc+ish) to input rows. WRITE_Y stores raw y (OTOT=64
// only). PARTIALS: BN partial sums into sumP[bid][OTOT]. POOL: norm+relu+max32.
template <int CIN, int OTOT, bool NORM_IN, bool WRITE_Y, bool PARTIALS, bool POOL>
__global__ __launch_bounds__(256)
__attribute__((amdgpu_waves_per_eu(1, 4)))
void k_mlp(
        const float* __restrict__ Yin, const float* __restrict__ w,
        const float* __restrict__ bias, const float* __restrict__ isc,
        const float* __restrict__ ish, float* __restrict__ Yout,
        float* __restrict__ sumP, float* __restrict__ sqP,
        const float* __restrict__ osc, const float* __restrict__ osh,
        float* __restrict__ out1) {
    const int h = blockIdx.y;            // 64-wide output half (0 or OTOT/64-1)
    const int ob = h * 64;               // output base
    __shared__ float wlds[CIN * 64];     // [c][o] for this half
    __shared__ float blds[64];
    __shared__ float iscl[NORM_IN ? CIN : 1], ishl[NORM_IN ? CIN : 1];
    __shared__ float oscl[POOL ? 64 : 1], oshl[POOL ? 64 : 1];
    __shared__ float lsum[PARTIALS ? 4 : 1][PARTIALS ? 64 : 1];
    __shared__ float lsq[PARTIALS ? 4 : 1][PARTIALS ? 64 : 1];
    for (int i = threadIdx.x; i < CIN * 64; i += 256) {
        int c = i >> 6, o = i & 63;
        wlds[i] = w[(ob + o) * CIN + c];
    }
    if (threadIdx.x < 64) {
        int o = threadIdx.x;
        blds[o] = bias[ob + o];
        if (POOL) { oscl[o] = osc[ob + o]; oshl[o] = osh[ob + o]; }
    }
    if (NORM_IN) {
        for (int i = threadIdx.x; i < CIN; i += 256) { iscl[i] = isc[i]; ishl[i] = ish[i]; }
    }
    __syncthreads();
    int r = blockIdx.x * 256 + threadIdx.x;
    float acc[64];
#pragma unroll
    for (int o = 0; o < 64; ++o) acc[o] = blds[o];
    const float4* r4 = (const float4*)(Yin + (size_t)r * CIN);
#pragma unroll 4
    for (int cc = 0; cc < CIN / 4; ++cc) {
        float4 x = r4[cc];
        float xs[4] = {x.x, x.y, x.z, x.w};
#pragma unroll
        for (int u = 0; u < 4; ++u) {
            int c = cc * 4 + u;
            float xv = xs[u];
            if (NORM_IN) xv = fmaxf(fmaf(xv, iscl[c], ishl[c]), 0.0f);
            const float* wr = &wlds[c * 64];
#pragma unroll
            for (int o = 0; o < 64; ++o) acc[o] = fmaf(xv, wr[o], acc[o]);
        }
    }
    if (WRITE_Y) {
        float4* yr = (float4*)(Yout + (size_t)r * OTOT + ob);
#pragma unroll
        for (int o4 = 0; o4 < 16; ++o4)
            yr[o4] = make_float4(acc[o4 * 4], acc[o4 * 4 + 1], acc[o4 * 4 + 2], acc[o4 * 4 + 3]);
    }
    if (PARTIALS) {
        int lane = threadIdx.x & 63, wvv = threadIdx.x >> 6;
#pragma unroll
        for (int o = 0; o < 64; ++o) {
            float v = acc[o], v2 = acc[o] * acc[o];
#pragma unroll
            for (int off = 1; off < 64; off <<= 1) { v += __shfl_xor(v, off); v2 += __shfl_xor(v2, off); }
            if (lane == 0) { lsum[wvv][o] = v; lsq[wvv][o] = v2; }
        }
        __syncthreads();
        if (threadIdx.x < 64) {
            int o = threadIdx.x;
            sumP[blockIdx.x * OTOT + ob + o] = lsum[0][o] + lsum[1][o] + lsum[2][o] + lsum[3][o];
            sqP[blockIdx.x * OTOT + ob + o]  = lsq[0][o] + lsq[1][o] + lsq[2][o] + lsq[3][o];
        }
    }
    if (POOL) {
        int b = r >> 15, s = (r >> 5) & (SS - 1);
#pragma unroll
        for (int o = 0; o < 64; ++o) {
            float v = fmaxf(fmaf(acc[o], oscl[o], oshl[o]), 0.0f);
#pragma unroll
            for (int off = 1; off < 32; off <<= 1) v = fmaxf(v, __shfl_xor(v, off));
            if ((threadIdx.x & 31) == 0)
                out1[((size_t)b * O3 + ob + o) * SS + s] = v;
        }
    }
}

// ---------------- finalize BN stats: 512 partials -> scale/shift ---------------
template <int COUT>
__global__ void k_finalize(const float* __restrict__ sumP, const float* __restrict__ sqP,
                           const float* __restrict__ g, const float* __restrict__ beta,
                           float* __restrict__ scale, float* __restrict__ shift) {
    __shared__ float ls[4][COUT], lq[4][COUT];
    int o = threadIdx.x % COUT, q = threadIdx.x / COUT;
    float s = 0.f, qq = 0.f;
    for (int bk = q; bk < 512; bk += 4) { s += sumP[bk * COUT + o]; qq += sqP[bk * COUT + o]; }
    ls[q][o] = s; lq[q][o] = qq;
    __syncthreads();
    if (q == 0) {
        s  = ls[0][o] + ls[1][o] + ls[2][o] + ls[3][o];
        qq = lq[0][o] + lq[1][o] + lq[2][o] + lq[3][o];
        const float inv = 1.0f / (float)RR;
        float mean = s * inv;
        float var = qq * inv - mean * mean;
        float sc = g[o] * rsqrtf(var + EPSF);
        scale[o] = sc;
        shift[o] = beta[o] - mean * sc;
    }
}

extern "C" void kernel_launch(void* const* d_in, const int* in_sizes, int n_in,
                              void* d_out, int out_size, void* d_ws, size_t ws_size,
                              hipStream_t stream) {
    const float* xyz = (const float*)d_in[0];
    const float* pts = (const float*)d_in[1];
    const float* w1  = (const float*)d_in[2];
    const float* b1  = (const float*)d_in[3];
    const float* g1  = (const float*)d_in[4];
    const float* bt1 = (const float*)d_in[5];
    const float* w2  = (const float*)d_in[6];
    const float* b2  = (const float*)d_in[7];
    const float* g2  = (const float*)d_in[8];
    const float* bt2 = (const float*)d_in[9];
    const float* w3  = (const float*)d_in[10];
    const float* b3  = (const float*)d_in[11];
    const float* g3  = (const float*)d_in[12];
    const float* bt3 = (const float*)d_in[13];
    float* out0 = (float*)d_out;                 // (B,3,S)
    float* out1 = out0 + BB * 3 * SS;            // (B,128,S)

    char* wsb = (char*)d_ws;
    size_t off = 0;
    auto alloc = [&](size_t bytes) {
        char* p = wsb + off;
        off += (bytes + 255) & ~(size_t)255;
        return p;
    };
    int*   fps_idx = (int*)alloc((size_t)BB * SS * 4);
    int*   ballidx = (int*)alloc((size_t)RR * 4);
    float* nxyz    = (float*)alloc((size_t)BB * SS * 3 * 4);
    float* sumP    = (float*)alloc((size_t)512 * 128 * 4);
    float* sqP     = (float*)alloc((size_t)512 * 128 * 4);
    float* sc1     = (float*)alloc(128 * 4);
    float* sh1     = (float*)alloc(128 * 4);
    float* sc2     = (float*)alloc(128 * 4);
    float* sh2     = (float*)alloc(128 * 4);
    float* sc3     = (float*)alloc(128 * 4);
    float* sh3     = (float*)alloc(128 * 4);
    float* Y1      = (float*)alloc((size_t)RR * 64 * 4);
    float* Y2      = (float*)alloc((size_t)RR * 64 * 4);
    float* ptsT    = Y2;   // ptsT (16 MB) lives in Y2's slot; Y2 written after gemm1

    k_tr<<<1024, 256, 0, stream>>>(pts, ptsT);
    k_fps<<<BB, FT, 0, stream>>>(xyz, fps_idx);
    k_newxyz<<<16, 256, 0, stream>>>(xyz, fps_idx, out0, nxyz);
    k_ball<<<1024, 256, 0, stream>>>(xyz, nxyz, ballidx);

    k_gemm1<<<512, 256, 0, stream>>>(xyz, ptsT, nxyz, ballidx, w1, b1, Y1, sumP, sqP);
    k_finalize<64><<<1, 256, 0, stream>>>(sumP, sqP, g1, bt1, sc1, sh1);

    k_mlp<64, 64, true, true, true, false><<<dim3(512, 1), 256, 0, stream>>>(
        Y1, w2, b2, sc1, sh1, Y2, sumP, sqP, nullptr, nullptr, nullptr);
    k_finalize<64><<<1, 256, 0, stream>>>(sumP, sqP, g2, bt2, sc2, sh2);

    k_mlp<64, 128, true, false, true, false><<<dim3(512, 2), 256, 0, stream>>>(
        Y2, w3, b3, sc2, sh2, nullptr, sumP, sqP, nullptr, nullptr, nullptr);
    k_finalize<128><<<1, 512, 0, stream>>>(sumP, sqP, g3, bt3, sc3, sh3);

    k_mlp<64, 128, true, false, false, true><<<dim3(512, 2), 256, 0, stream>>>(
        Y2, w3, b3, sc2, sh2, nullptr, nullptr, nullptr, sc3, sh3, out1);
}

// Round 8
// 1962.241 us; speedup vs baseline: 1.2141x; 1.2141x over previous
//
#include <hip/hip_runtime.h>
#include <hip/hip_bf16.h>
#include <stdint.h>

#define NPT   16384   // N
#define BB    4
#define SS    1024    // NPOINT
#define KK    32      // NSAMPLE
#define RR    (BB*SS*KK) // 131072 rows
#define C1    67
#define O1    64
#define O3    128
#define EPSF  1e-5f
#define R2F   0.09f   // f32(0.09)
#define FT    1024    // FPS threads/block
#define FE    16      // FPS elements/thread
#define BIGI  0x7fffffff

#define REP16(M) M(0) M(1) M(2) M(3) M(4) M(5) M(6) M(7) \
                 M(8) M(9) M(10) M(11) M(12) M(13) M(14) M(15)
#define REP16R(M) M(15) M(14) M(13) M(12) M(11) M(10) M(9) M(8) \
                  M(7) M(6) M(5) M(4) M(3) M(2) M(1) M(0)

// butterfly f32 max across a wave: 5 ds_swizzle levels + cross-32 shuffle
#define WMAX5(v) { \
    v = fmaxf(v, __int_as_float(__builtin_amdgcn_ds_swizzle(__float_as_int(v), 0x041F))); \
    v = fmaxf(v, __int_as_float(__builtin_amdgcn_ds_swizzle(__float_as_int(v), 0x081F))); \
    v = fmaxf(v, __int_as_float(__builtin_amdgcn_ds_swizzle(__float_as_int(v), 0x101F))); \
    v = fmaxf(v, __int_as_float(__builtin_amdgcn_ds_swizzle(__float_as_int(v), 0x201F))); \
    v = fmaxf(v, __int_as_float(__builtin_amdgcn_ds_swizzle(__float_as_int(v), 0x401F))); }

// ---------------- FPS: one block/batch, f32-max reduce + equality argfind -----
// R4-R7 post-mortem: four different register/LDS layouts all ran ~1880us ->
// bottleneck is per-iteration VALU count + the serial u64 packed-key reduce
// (10 levels of 2x ds_bpermute + u64 cmp/select, in lockstep in every wave).
// This version: (1) phase-1 tracks only the f32 max (no per-element index
// bookkeeping: -3 VALU/elem); (2) value reduce is f32 fmax via documented
// ds_swizzle butterfly (1 v_max/level); (3) the argmax index is recovered once
// per iteration by an exact equality scan (fmax returns an input bitwise, so
// M is the exact winning dj) + LDS atomicMin for global lowest-index tiebreak
// == jnp.argmax first-occurrence semantics.
__global__ __launch_bounds__(FT)
__attribute__((amdgpu_waves_per_eu(4, 4)))
void k_fps(const float* __restrict__ xyz, int* __restrict__ fps_idx) {
    const int b = blockIdx.x;
    const int tid = threadIdx.x;
    const int lane = tid & 63, wv = tid >> 6;      // 16 waves
    const float* xb = xyz + (size_t)b * 3 * NPT;

    __shared__ float2 sxy[NPT];                    // 128 KB: (x,y) interleaved
    __shared__ float s_red[16];                    // per-wave max
    __shared__ int s_win[2];                       // double-buffered argmin cell

#define DECLV(i) float Z##i, D##i;
    REP16(DECLV)
#define INITV(i) { int n = (i) * FT + tid; \
                   float xx = xb[n]; \
                   float yy = xb[NPT + n]; \
                   float zz = xb[2 * NPT + n]; \
                   sxy[n] = make_float2(xx, yy); \
                   asm volatile("" : "+v"(zz)); \
                   Z##i = zz; D##i = 1e10f; }
    REP16(INITV)
    if (tid == 0) { s_win[0] = BIGI; s_win[1] = BIGI; }
    __syncthreads();                               // sxy + s_win visible

    int p = 0;
    int far = 0;
    float2 c0 = sxy[0];
    float cx = c0.x, cy = c0.y, cz = xb[2 * NPT];
    for (int it = 0; it < SS; ++it) {
        if (tid == 0) fps_idx[b * SS + it] = far;
        float bd = -1.0f;
        // exact reference arithmetic: (dx*dx + dy*dy) + dz*dz, no FMA
#define UPDV(i) { float2 xy = sxy[(i) * FT + tid]; \
                  float dx = __fsub_rn(xy.x, cx); \
                  float dy = __fsub_rn(xy.y, cy); \
                  float dz = __fsub_rn(Z##i, cz); \
                  float d = __fadd_rn(__fadd_rn(__fmul_rn(dx, dx), __fmul_rn(dy, dy)), \
                                      __fmul_rn(dz, dz)); \
                  float dj = fminf(D##i, d); D##i = dj; \
                  bd = fmaxf(bd, dj); }
        REP16(UPDV)

        // wave max (f32 butterfly), then per-wave partial to LDS
        WMAX5(bd)
        bd = fmaxf(bd, __shfl_xor(bd, 32));
        if (lane == 0) s_red[wv] = bd;
        __syncthreads();                  // barrier 1: partials ready
        if (tid == 0) s_win[p ^ 1] = BIGI;             // prep next iter's cell
        // merge 16 partials: every 16-lane group holds all 16 -> 4 xor levels
        float M = s_red[lane & 15];
        M = fmaxf(M, __int_as_float(__builtin_amdgcn_ds_swizzle(__float_as_int(M), 0x041F)));
        M = fmaxf(M, __int_as_float(__builtin_amdgcn_ds_swizzle(__float_as_int(M), 0x081F)));
        M = fmaxf(M, __int_as_float(__builtin_amdgcn_ds_swizzle(__float_as_int(M), 0x101F)));
        M = fmaxf(M, __int_as_float(__builtin_amdgcn_ds_swizzle(__float_as_int(M), 0x201F)));
        // find lowest local index whose (updated) dist equals M exactly
        int bn = BIGI;
#define SCANV(i) { bn = (D##i == M) ? ((i) * FT + tid) : bn; }
        REP16R(SCANV)
        if (bn != BIGI) atomicMin(&s_win[p], bn);      // typically 1 thread
        __syncthreads();                  // barrier 2: winner ready
        far = s_win[p];
        float2 cxy = sxy[far];            // uniform addr -> LDS broadcast
        cx = cxy.x; cy = cxy.y;
        cz = xb[2 * NPT + far];           // z plane from L2
        p ^= 1;
    }
#undef DECLV
#undef INITV
#undef UPDV
#undef SCANV
}

// ---------------- gather new_xyz: output0 (B,3,S) + ws copy (b,s,3) ------------
__global__ void k_newxyz(const float* __restrict__ xyz, const int* __restrict__ fps_idx,
                         float* __restrict__ out0, float* __restrict__ nxyz) {
    int g = blockIdx.x * blockDim.x + threadIdx.x;
    if (g >= BB * SS) return;
    int b = g / SS, s = g % SS;
    int id = fps_idx[g];
    const float* xb = xyz + (size_t)b * 3 * NPT;
#pragma unroll
    for (int c = 0; c < 3; ++c) {
        float v = xb[c * NPT + id];
        out0[(size_t)b * 3 * SS + c * SS + s] = v;
        nxyz[g * 3 + c] = v;
    }
}

// ---------------- ball query: one wave per centroid, ballot ranking ------------
__global__ __launch_bounds__(256) void k_ball(const float* __restrict__ xyz,
                                              const float* __restrict__ nxyz,
                                              int* __restrict__ ballidx) {
    int wid = (blockIdx.x * 256 + threadIdx.x) >> 6;   // 0..4095
    int lane = threadIdx.x & 63;
    int b = wid >> 10;
    const float* xb = xyz + (size_t)b * 3 * NPT;
    float nx = nxyz[wid * 3], ny = nxyz[wid * 3 + 1], nz = nxyz[wid * 3 + 2];
    int* out = ballidx + (size_t)wid * KK;
    int cnt = 0;
    int first = -1;
    for (int base = 0; base < NPT; base += 64) {
        int n = base + lane;
        float dx = __fsub_rn(nx, xb[n]);
        float dy = __fsub_rn(ny, xb[NPT + n]);
        float dz = __fsub_rn(nz, xb[2 * NPT + n]);
        float d = __fadd_rn(__fadd_rn(__fmul_rn(dx, dx), __fmul_rn(dy, dy)),
                            __fmul_rn(dz, dz));
        bool hit = !(d > R2F);            // excluded iff sqr > r^2 (matches ref)
        unsigned long long mask = __ballot(hit);
        if (mask) {
            if (first < 0) first = base + __builtin_ctzll(mask);
            int rank = cnt + __popcll(mask & ((1ull << lane) - 1ull));
            if (hit && rank < KK) out[rank] = n;
            cnt += __popcll(mask);
        }
        if (cnt >= KK) break;
    }
    if (lane >= cnt && lane < KK) out[lane] = first;   // pad with first hit
}

// ---------------- transpose pts (B,64,N) -> ptsT (B,N,64) ----------------------
__global__ __launch_bounds__(256) void k_tr(const float* __restrict__ pts,
                                            float* __restrict__ ptsT) {
    __shared__ float t[64][65];
    int b = blockIdx.x >> 8, n0 = (blockIdx.x & 255) << 6;
    const float* pb = pts + (size_t)b * 64 * NPT;
    int tx = threadIdx.x & 63, ty = threadIdx.x >> 6;  // ty in 0..3
#pragma unroll
    for (int k = 0; k < 16; ++k) {
        int c = ty * 16 + k;
        t[c][tx] = pb[(size_t)c * NPT + n0 + tx];      // coalesced in n
    }
    __syncthreads();
#pragma unroll
    for (int k = 0; k < 16; ++k) {
        int n = ty * 16 + k;
        ptsT[((size_t)b * NPT + n0 + n) * 64 + tx] = t[tx][n];  // coalesced in c
    }
}

// ---------------- layer1: gather + GEMM(67->64) + BN partial sums --------------
__global__ __launch_bounds__(256)
__attribute__((amdgpu_waves_per_eu(1, 4)))
void k_gemm1(const float* __restrict__ xyz,
        const float* __restrict__ ptsT, const float* __restrict__ nxyz,
        const int* __restrict__ ballidx, const float* __restrict__ w,
        const float* __restrict__ bias, float* __restrict__ Y,
        float* __restrict__ sumP, float* __restrict__ sqP) {
    __shared__ float wlds[C1 * O1];   // [c][o]
    __shared__ float blds[O1];
    __shared__ float lsum[4][O1];
    __shared__ float lsq[4][O1];
    for (int i = threadIdx.x; i < C1 * O1; i += 256) {
        int c = i >> 6, o = i & 63;
        wlds[i] = w[o * C1 + c];
    }
    if (threadIdx.x < O1) blds[threadIdx.x] = bias[threadIdx.x];
    __syncthreads();
    int r = blockIdx.x * 256 + threadIdx.x;
    int b = r >> 15;
    int g = r >> 5;
    int id = ballidx[r];
    const float* xb = xyz + (size_t)b * 3 * NPT;
    float acc[O1];
#pragma unroll
    for (int o = 0; o < O1; ++o) acc[o] = blds[o];
#pragma unroll
    for (int c = 0; c < 3; ++c) {
        float xv = xb[c * NPT + id] - nxyz[g * 3 + c];
        const float* wr = &wlds[c * O1];
#pragma unroll
        for (int o = 0; o < O1; ++o) acc[o] = fmaf(xv, wr[o], acc[o]);
    }
    const float4* p4 = (const float4*)(ptsT + ((size_t)b * NPT + id) * 64);
#pragma unroll 4
    for (int cc = 0; cc < 16; ++cc) {
        float4 x = p4[cc];
        float xs[4] = {x.x, x.y, x.z, x.w};
#pragma unroll
        for (int u = 0; u < 4; ++u) {
            const float* wr = &wlds[(3 + cc * 4 + u) * O1];
#pragma unroll
            for (int o = 0; o < O1; ++o) acc[o] = fmaf(xs[u], wr[o], acc[o]);
        }
    }
    float4* yr = (float4*)(Y + (size_t)r * O1);
#pragma unroll
    for (int o4 = 0; o4 < O1 / 4; ++o4)
        yr[o4] = make_float4(acc[o4 * 4], acc[o4 * 4 + 1], acc[o4 * 4 + 2], acc[o4 * 4 + 3]);
    int lane = threadIdx.x & 63, wvv = threadIdx.x >> 6;
#pragma unroll
    for (int o = 0; o < O1; ++o) {
        float v = acc[o], v2 = acc[o] * acc[o];
#pragma unroll
        for (int off = 1; off < 64; off <<= 1) { v += __shfl_xor(v, off); v2 += __shfl_xor(v2, off); }
        if (lane == 0) { lsum[wvv][o] = v; lsq[wvv][o] = v2; }
    }
    __syncthreads();
    if (threadIdx.x < O1) {
        int o = threadIdx.x;
        sumP[blockIdx.x * O1 + o] = lsum[0][o] + lsum[1][o] + lsum[2][o] + lsum[3][o];
        sqP[blockIdx.x * O1 + o]  = lsq[0][o] + lsq[1][o] + lsq[2][o] + lsq[3][o];
    }
}

// ---------------- generic MLP layer: 64 outputs PER BLOCK ----------------------
// OTOT total outputs; blockIdx.y selects which 64-wide half this block computes.
// NORM_IN applies relu(x*isc+ish) to input rows. WRITE_Y stores raw y (OTOT=64
// only). PARTIALS: BN partial sums into sumP[bid][OTOT]. POOL: norm+relu+max32.
template <int CIN, int OTOT, bool NORM_IN, bool WRITE_Y, bool PARTIALS, bool POOL>
__global__ __launch_bounds__(256)
__attribute__((amdgpu_waves_per_eu(1, 4)))
void k_mlp(
        const float* __restrict__ Yin, const float* __restrict__ w,
        const float* __restrict__ bias, const float* __restrict__ isc,
        const float* __restrict__ ish, float* __restrict__ Yout,
        float* __restrict__ sumP, float* __restrict__ sqP,
        const float* __restrict__ osc, const float* __restrict__ osh,
        float* __restrict__ out1) {
    const int h = blockIdx.y;            // 64-wide output half (0 or OTOT/64-1)
    const int ob = h * 64;               // output base
    __shared__ float wlds[CIN * 64];     // [c][o] for this half
    __shared__ float blds[64];
    __shared__ float iscl[NORM_IN ? CIN : 1], ishl[NORM_IN ? CIN : 1];
    __shared__ float oscl[POOL ? 64 : 1], oshl[POOL ? 64 : 1];
    __shared__ float lsum[PARTIALS ? 4 : 1][PARTIALS ? 64 : 1];
    __shared__ float lsq[PARTIALS ? 4 : 1][PARTIALS ? 64 : 1];
    for (int i = threadIdx.x; i < CIN * 64; i += 256) {
        int c = i >> 6, o = i & 63;
        wlds[i] = w[(ob + o) * CIN + c];
    }
    if (threadIdx.x < 64) {
        int o = threadIdx.x;
        blds[o] = bias[ob + o];
        if (POOL) { oscl[o] = osc[ob + o]; oshl[o] = osh[ob + o]; }
    }
    if (NORM_IN) {
        for (int i = threadIdx.x; i < CIN; i += 256) { iscl[i] = isc[i]; ishl[i] = ish[i]; }
    }
    __syncthreads();
    int r = blockIdx.x * 256 + threadIdx.x;
    float acc[64];
#pragma unroll
    for (int o = 0; o < 64; ++o) acc[o] = blds[o];
    const float4* r4 = (const float4*)(Yin + (size_t)r * CIN);
#pragma unroll 4
    for (int cc = 0; cc < CIN / 4; ++cc) {
        float4 x = r4[cc];
        float xs[4] = {x.x, x.y, x.z, x.w};
#pragma unroll
        for (int u = 0; u < 4; ++u) {
            int c = cc * 4 + u;
            float xv = xs[u];
            if (NORM_IN) xv = fmaxf(fmaf(xv, iscl[c], ishl[c]), 0.0f);
            const float* wr = &wlds[c * 64];
#pragma unroll
            for (int o = 0; o < 64; ++o) acc[o] = fmaf(xv, wr[o], acc[o]);
        }
    }
    if (WRITE_Y) {
        float4* yr = (float4*)(Yout + (size_t)r * OTOT + ob);
#pragma unroll
        for (int o4 = 0; o4 < 16; ++o4)
            yr[o4] = make_float4(acc[o4 * 4], acc[o4 * 4 + 1], acc[o4 * 4 + 2], acc[o4 * 4 + 3]);
    }
    if (PARTIALS) {
        int lane = threadIdx.x & 63, wvv = threadIdx.x >> 6;
#pragma unroll
        for (int o = 0; o < 64; ++o) {
            float v = acc[o], v2 = acc[o] * acc[o];
#pragma unroll
            for (int off = 1; off < 64; off <<= 1) { v += __shfl_xor(v, off); v2 += __shfl_xor(v2, off); }
            if (lane == 0) { lsum[wvv][o] = v; lsq[wvv][o] = v2; }
        }
        __syncthreads();
        if (threadIdx.x < 64) {
            int o = threadIdx.x;
            sumP[blockIdx.x * OTOT + ob + o] = lsum[0][o] + lsum[1][o] + lsum[2][o] + lsum[3][o];
            sqP[blockIdx.x * OTOT + ob + o]  = lsq[0][o] + lsq[1][o] + lsq[2][o] + lsq[3][o];
        }
    }
    if (POOL) {
        int b = r >> 15, s = (r >> 5) & (SS - 1);
#pragma unroll
        for (int o = 0; o < 64; ++o) {
            float v = fmaxf(fmaf(acc[o], oscl[o], oshl[o]), 0.0f);
#pragma unroll
            for (int off = 1; off < 32; off <<= 1) v = fmaxf(v, __shfl_xor(v, off));
            if ((threadIdx.x & 31) == 0)
                out1[((size_t)b * O3 + ob + o) * SS + s] = v;
        }
    }
}

// ---------------- finalize BN stats: 512 partials -> scale/shift ---------------
template <int COUT>
__global__ void k_finalize(const float* __restrict__ sumP, const float* __restrict__ sqP,
                           const float* __restrict__ g, const float* __restrict__ beta,
                           float* __restrict__ scale, float* __restrict__ shift) {
    __shared__ float ls[4][COUT], lq[4][COUT];
    int o = threadIdx.x % COUT, q = threadIdx.x / COUT;
    float s = 0.f, qq = 0.f;
    for (int bk = q; bk < 512; bk += 4) { s += sumP[bk * COUT + o]; qq += sqP[bk * COUT + o]; }
    ls[q][o] = s; lq[q][o] = qq;
    __syncthreads();
    if (q == 0) {
        s  = ls[0][o] + ls[1][o] + ls[2][o] + ls[3][o];
        qq = lq[0][o] + lq[1][o] + lq[2][o] + lq[3][o];
        const float inv = 1.0f / (float)RR;
        float mean = s * inv;
        float var = qq * inv - mean * mean;
        float sc = g[o] * rsqrtf(var + EPSF);
        scale[o] = sc;
        shift[o] = beta[o] - mean * sc;
    }
}

extern "C" void kernel_launch(void* const* d_in, const int* in_sizes, int n_in,
                              void* d_out, int out_size, void* d_ws, size_t ws_size,
                              hipStream_t stream) {
    const float* xyz = (const float*)d_in[0];
    const float* pts = (const float*)d_in[1];
    const float* w1  = (const float*)d_in[2];
    const float* b1  = (const float*)d_in[3];
    const float* g1  = (const float*)d_in[4];
    const float* bt1 = (const float*)d_in[5];
    const float* w2  = (const float*)d_in[6];
    const float* b2  = (const float*)d_in[7];
    const float* g2  = (const float*)d_in[8];
    const float* bt2 = (const float*)d_in[9];
    const float* w3  = (const float*)d_in[10];
    const float* b3  = (const float*)d_in[11];
    const float* g3  = (const float*)d_in[12];
    const float* bt3 = (const float*)d_in[13];
    float* out0 = (float*)d_out;                 // (B,3,S)
    float* out1 = out0 + BB * 3 * SS;            // (B,128,S)

    char* wsb = (char*)d_ws;
    size_t off = 0;
    auto alloc = [&](size_t bytes) {
        char* p = wsb + off;
        off += (bytes + 255) & ~(size_t)255;
        return p;
    };
    int*   fps_idx = (int*)alloc((size_t)BB * SS * 4);
    int*   ballidx = (int*)alloc((size_t)RR * 4);
    float* nxyz    = (float*)alloc((size_t)BB * SS * 3 * 4);
    float* sumP    = (float*)alloc((size_t)512 * 128 * 4);
    float* sqP     = (float*)alloc((size_t)512 * 128 * 4);
    float* sc1     = (float*)alloc(128 * 4);
    float* sh1     = (float*)alloc(128 * 4);
    float* sc2     = (float*)alloc(128 * 4);
    float* sh2     = (float*)alloc(128 * 4);
    float* sc3     = (float*)alloc(128 * 4);
    float* sh3     = (float*)alloc(128 * 4);
    float* Y1      = (float*)alloc((size_t)RR * 64 * 4);
    float* Y2      = (float*)alloc((size_t)RR * 64 * 4);
    float* ptsT    = Y2;   // ptsT (16 MB) lives in Y2's slot; Y2 written after gemm1

    k_tr<<<1024, 256, 0, stream>>>(pts, ptsT);
    k_fps<<<BB, FT, 0, stream>>>(xyz, fps_idx);
    k_newxyz<<<16, 256, 0, stream>>>(xyz, fps_idx, out0, nxyz);
    k_ball<<<1024, 256, 0, stream>>>(xyz, nxyz, ballidx);

    k_gemm1<<<512, 256, 0, stream>>>(xyz, ptsT, nxyz, ballidx, w1, b1, Y1, sumP, sqP);
    k_finalize<64><<<1, 256, 0, stream>>>(sumP, sqP, g1, bt1, sc1, sh1);

    k_mlp<64, 64, true, true, true, false><<<dim3(512, 1), 256, 0, stream>>>(
        Y1, w2, b2, sc1, sh1, Y2, sumP, sqP, nullptr, nullptr, nullptr);
    k_finalize<64><<<1, 256, 0, stream>>>(sumP, sqP, g2, bt2, sc2, sh2);

    k_mlp<64, 128, true, false, true, false><<<dim3(512, 2), 256, 0, stream>>>(
        Y2, w3, b3, sc2, sh2, nullptr, sumP, sqP, nullptr, nullptr, nullptr);
    k_finalize<128><<<1, 512, 0, stream>>>(sumP, sqP, g3, bt3, sc3, sh3);

    k_mlp<64, 128, true, false, false, true><<<dim3(512, 2), 256, 0, stream>>>(
        Y2, w3, b3, sc2, sh2, nullptr, nullptr, nullptr, sc3, sh3, out1);
}

// Round 9
// 1801.347 us; speedup vs baseline: 1.3225x; 1.0893x over previous
//
#include <hip/hip_runtime.h>
#include <hip/hip_bf16.h>
#include <stdint.h>

#define NPT   16384   // N
#define BB    4
#define SS    1024    // NPOINT
#define KK    32      // NSAMPLE
#define RR    (BB*SS*KK) // 131072 rows
#define C1    67
#define O1    64
#define O3    128
#define EPSF  1e-5f
#define R2F   0.09f   // f32(0.09)
#define FT    1024    // FPS threads/block
#define FE    16      // FPS elements/thread
#define BIGI  0x7fffffff

#define REP16(M) M(0) M(1) M(2) M(3) M(4) M(5) M(6) M(7) \
                 M(8) M(9) M(10) M(11) M(12) M(13) M(14) M(15)
#define REP16R(M) M(15) M(14) M(13) M(12) M(11) M(10) M(9) M(8) \
                  M(7) M(6) M(5) M(4) M(3) M(2) M(1) M(0)

// butterfly f32 max across a wave: 5 ds_swizzle levels + cross-32 shuffle
#define WMAX5(v) { \
    v = fmaxf(v, __int_as_float(__builtin_amdgcn_ds_swizzle(__float_as_int(v), 0x041F))); \
    v = fmaxf(v, __int_as_float(__builtin_amdgcn_ds_swizzle(__float_as_int(v), 0x081F))); \
    v = fmaxf(v, __int_as_float(__builtin_amdgcn_ds_swizzle(__float_as_int(v), 0x101F))); \
    v = fmaxf(v, __int_as_float(__builtin_amdgcn_ds_swizzle(__float_as_int(v), 0x201F))); \
    v = fmaxf(v, __int_as_float(__builtin_amdgcn_ds_swizzle(__float_as_int(v), 0x401F))); }

// ---------------- FPS: single-cell atomic reduce, z rides the argmin key ------
// R8 post-mortem (3540 cyc/iter, VALU-issue-bound): remaining fat = unguarded
// equality scan (32 VALU/thread/iter), s_red+4-swizzle merge (~300 serial cyc),
// and the cz L2 load (~200 serial cyc/iter). This round:
//  - per-wave atomicMax(int) of f32 bits on ONE cell (monotone for >=0 floats);
//    M comes back in a single broadcast read.
//  - scan runs only in threads whose OWN max == M (1 wave of 16, usually).
//  - winner index+z travel together in one u64 atomicMin key (bn<<32 | z_bits):
//    equal bn => equal payload, so min-by-index is exact; z never touches L2.
//  - tree fmax (depth 4) instead of a 16-deep serial chain.
__global__ __launch_bounds__(FT)
__attribute__((amdgpu_waves_per_eu(4, 4)))
void k_fps(const float* __restrict__ xyz, int* __restrict__ fps_idx) {
    const int b = blockIdx.x;
    const int tid = threadIdx.x;
    const int lane = tid & 63;
    const float* xb = xyz + (size_t)b * 3 * NPT;

    __shared__ float2 sxy[NPT];                    // 128 KB: (x,y) interleaved
    __shared__ int s_M[2];                         // double-buffered max cell
    __shared__ unsigned long long s_wz[2];         // double-buffered (idx,z) cell

#define DECLV(i) float Z##i, D##i;
    REP16(DECLV)
#define INITV(i) { int n = (i) * FT + tid; \
                   float xx = xb[n]; \
                   float yy = xb[NPT + n]; \
                   float zz = xb[2 * NPT + n]; \
                   sxy[n] = make_float2(xx, yy); \
                   asm volatile("" : "+v"(zz)); \
                   Z##i = zz; D##i = 1e10f; }
    REP16(INITV)
    if (tid == 0) { s_M[0] = 0; s_M[1] = 0; s_wz[0] = ~0ull; s_wz[1] = ~0ull; }
    __syncthreads();                               // sxy + cells visible

    int p = 0;
    int far = 0;
    float2 c0 = sxy[0];
    float cx = c0.x, cy = c0.y, cz = xb[2 * NPT];
    for (int it = 0; it < SS; ++it) {
        if (tid == 0) fps_idx[b * SS + it] = far;
        // exact reference arithmetic: (dx*dx + dy*dy) + dz*dz, no FMA
#define UPDV(i) { float2 xy = sxy[(i) * FT + tid]; \
                  float dx = __fsub_rn(xy.x, cx); \
                  float dy = __fsub_rn(xy.y, cy); \
                  float dz = __fsub_rn(Z##i, cz); \
                  float d = __fadd_rn(__fadd_rn(__fmul_rn(dx, dx), __fmul_rn(dy, dy)), \
                                      __fmul_rn(dz, dz)); \
                  D##i = fminf(D##i, d); }
        REP16(UPDV)
        // depth-4 tree max of the 16 updated dists (max3-fusable pairs)
        float m0 = fmaxf(fmaxf(D0, D1), fmaxf(D2, D3));
        float m1 = fmaxf(fmaxf(D4, D5), fmaxf(D6, D7));
        float m2 = fmaxf(fmaxf(D8, D9), fmaxf(D10, D11));
        float m3 = fmaxf(fmaxf(D12, D13), fmaxf(D14, D15));
        float tbd = fmaxf(fmaxf(m0, m1), fmaxf(m2, m3));   // thread max

        float bd = tbd;
        WMAX5(bd)
        bd = fmaxf(bd, __shfl_xor(bd, 32));                // wave max
        if (lane == 0) atomicMax(&s_M[p], __float_as_int(bd));
        __syncthreads();                  // barrier A: global max ready
        if (tid == 0) { s_M[p ^ 1] = 0; s_wz[p ^ 1] = ~0ull; }  // prep next iter
        float Mf = __int_as_float(s_M[p]);
        if (tbd == Mf) {                  // only threads holding the max scan
            int bn = BIGI; float zw = 0.0f;
#define SCANV(i) { bool m = (D##i == Mf); \
                   bn = m ? ((i) * FT + tid) : bn; \
                   zw = m ? Z##i : zw; }
            REP16R(SCANV)
            atomicMin(&s_wz[p], ((unsigned long long)(unsigned)bn << 32) |
                                (unsigned long long)__float_as_uint(zw));
        }
        __syncthreads();                  // barrier B: winner ready
        unsigned long long wz = s_wz[p];
        far = (int)(wz >> 32);
        cz = __uint_as_float((unsigned)wz);
        float2 cxy = sxy[far];            // uniform addr -> LDS broadcast
        cx = cxy.x; cy = cxy.y;
        p ^= 1;
    }
#undef DECLV
#undef INITV
#undef UPDV
#undef SCANV
}

// ---------------- gather new_xyz: output0 (B,3,S) + ws copy (b,s,3) ------------
__global__ void k_newxyz(const float* __restrict__ xyz, const int* __restrict__ fps_idx,
                         float* __restrict__ out0, float* __restrict__ nxyz) {
    int g = blockIdx.x * blockDim.x + threadIdx.x;
    if (g >= BB * SS) return;
    int b = g / SS, s = g % SS;
    int id = fps_idx[g];
    const float* xb = xyz + (size_t)b * 3 * NPT;
#pragma unroll
    for (int c = 0; c < 3; ++c) {
        float v = xb[c * NPT + id];
        out0[(size_t)b * 3 * SS + c * SS + s] = v;
        nxyz[g * 3 + c] = v;
    }
}

// ---------------- ball query: one wave per centroid, ballot ranking ------------
__global__ __launch_bounds__(256) void k_ball(const float* __restrict__ xyz,
                                              const float* __restrict__ nxyz,
                                              int* __restrict__ ballidx) {
    int wid = (blockIdx.x * 256 + threadIdx.x) >> 6;   // 0..4095
    int lane = threadIdx.x & 63;
    int b = wid >> 10;
    const float* xb = xyz + (size_t)b * 3 * NPT;
    float nx = nxyz[wid * 3], ny = nxyz[wid * 3 + 1], nz = nxyz[wid * 3 + 2];
    int* out = ballidx + (size_t)wid * KK;
    int cnt = 0;
    int first = -1;
    for (int base = 0; base < NPT; base += 64) {
        int n = base + lane;
        float dx = __fsub_rn(nx, xb[n]);
        float dy = __fsub_rn(ny, xb[NPT + n]);
        float dz = __fsub_rn(nz, xb[2 * NPT + n]);
        float d = __fadd_rn(__fadd_rn(__fmul_rn(dx, dx), __fmul_rn(dy, dy)),
                            __fmul_rn(dz, dz));
        bool hit = !(d > R2F);            // excluded iff sqr > r^2 (matches ref)
        unsigned long long mask = __ballot(hit);
        if (mask) {
            if (first < 0) first = base + __builtin_ctzll(mask);
            int rank = cnt + __popcll(mask & ((1ull << lane) - 1ull));
            if (hit && rank < KK) out[rank] = n;
            cnt += __popcll(mask);
        }
        if (cnt >= KK) break;
    }
    if (lane >= cnt && lane < KK) out[lane] = first;   // pad with first hit
}

// ---------------- transpose pts (B,64,N) -> ptsT (B,N,64) ----------------------
__global__ __launch_bounds__(256) void k_tr(const float* __restrict__ pts,
                                            float* __restrict__ ptsT) {
    __shared__ float t[64][65];
    int b = blockIdx.x >> 8, n0 = (blockIdx.x & 255) << 6;
    const float* pb = pts + (size_t)b * 64 * NPT;
    int tx = threadIdx.x & 63, ty = threadIdx.x >> 6;  // ty in 0..3
#pragma unroll
    for (int k = 0; k < 16; ++k) {
        int c = ty * 16 + k;
        t[c][tx] = pb[(size_t)c * NPT + n0 + tx];      // coalesced in n
    }
    __syncthreads();
#pragma unroll
    for (int k = 0; k < 16; ++k) {
        int n = ty * 16 + k;
        ptsT[((size_t)b * NPT + n0 + n) * 64 + tx] = t[tx][n];  // coalesced in c
    }
}

// ---------------- layer1: gather + GEMM(67->64) + BN partial sums --------------
__global__ __launch_bounds__(256)
__attribute__((amdgpu_waves_per_eu(1, 4)))
void k_gemm1(const float* __restrict__ xyz,
        const float* __restrict__ ptsT, const float* __restrict__ nxyz,
        const int* __restrict__ ballidx, const float* __restrict__ w,
        const float* __restrict__ bias, float* __restrict__ Y,
        float* __restrict__ sumP, float* __restrict__ sqP) {
    __shared__ float wlds[C1 * O1];   // [c][o]
    __shared__ float blds[O1];
    __shared__ float lsum[4][O1];
    __shared__ float lsq[4][O1];
    for (int i = threadIdx.x; i < C1 * O1; i += 256) {
        int c = i >> 6, o = i & 63;
        wlds[i] = w[o * C1 + c];
    }
    if (threadIdx.x < O1) blds[threadIdx.x] = bias[threadIdx.x];
    __syncthreads();
    int r = blockIdx.x * 256 + threadIdx.x;
    int b = r >> 15;
    int g = r >> 5;
    int id = ballidx[r];
    const float* xb = xyz + (size_t)b * 3 * NPT;
    float acc[O1];
#pragma unroll
    for (int o = 0; o < O1; ++o) acc[o] = blds[o];
#pragma unroll
    for (int c = 0; c < 3; ++c) {
        float xv = xb[c * NPT + id] - nxyz[g * 3 + c];
        const float* wr = &wlds[c * O1];
#pragma unroll
        for (int o = 0; o < O1; ++o) acc[o] = fmaf(xv, wr[o], acc[o]);
    }
    const float4* p4 = (const float4*)(ptsT + ((size_t)b * NPT + id) * 64);
#pragma unroll 4
    for (int cc = 0; cc < 16; ++cc) {
        float4 x = p4[cc];
        float xs[4] = {x.x, x.y, x.z, x.w};
#pragma unroll
        for (int u = 0; u < 4; ++u) {
            const float* wr = &wlds[(3 + cc * 4 + u) * O1];
#pragma unroll
            for (int o = 0; o < O1; ++o) acc[o] = fmaf(xs[u], wr[o], acc[o]);
        }
    }
    float4* yr = (float4*)(Y + (size_t)r * O1);
#pragma unroll
    for (int o4 = 0; o4 < O1 / 4; ++o4)
        yr[o4] = make_float4(acc[o4 * 4], acc[o4 * 4 + 1], acc[o4 * 4 + 2], acc[o4 * 4 + 3]);
    int lane = threadIdx.x & 63, wvv = threadIdx.x >> 6;
#pragma unroll
    for (int o = 0; o < O1; ++o) {
        float v = acc[o], v2 = acc[o] * acc[o];
#pragma unroll
        for (int off = 1; off < 64; off <<= 1) { v += __shfl_xor(v, off); v2 += __shfl_xor(v2, off); }
        if (lane == 0) { lsum[wvv][o] = v; lsq[wvv][o] = v2; }
    }
    __syncthreads();
    if (threadIdx.x < O1) {
        int o = threadIdx.x;
        sumP[blockIdx.x * O1 + o] = lsum[0][o] + lsum[1][o] + lsum[2][o] + lsum[3][o];
        sqP[blockIdx.x * O1 + o]  = lsq[0][o] + lsq[1][o] + lsq[2][o] + lsq[3][o];
    }
}

// ---------------- generic MLP layer: 64 outputs PER BLOCK ----------------------
// OTOT total outputs; blockIdx.y selects which 64-wide half this block computes.
// NORM_IN applies relu(x*isc+ish) to input rows. WRITE_Y stores raw y.
// PARTIALS: BN partial sums. MAXOUT: raw max over each 32-row group -> ymax
// (layout (B,O3,S)); valid because the later relu(y*sc+sh) is monotone (sc>0),
// so max commutes with it bitwise -- deletes the whole pass-B GEMM.
template <int CIN, int OTOT, bool NORM_IN, bool WRITE_Y, bool PARTIALS, bool MAXOUT>
__global__ __launch_bounds__(256)
__attribute__((amdgpu_waves_per_eu(1, 4)))
void k_mlp(
        const float* __restrict__ Yin, const float* __restrict__ w,
        const float* __restrict__ bias, const float* __restrict__ isc,
        const float* __restrict__ ish, float* __restrict__ Yout,
        float* __restrict__ sumP, float* __restrict__ sqP,
        float* __restrict__ ymax) {
    const int h = blockIdx.y;            // 64-wide output half (0 or OTOT/64-1)
    const int ob = h * 64;               // output base
    __shared__ float wlds[CIN * 64];     // [c][o] for this half
    __shared__ float blds[64];
    __shared__ float iscl[NORM_IN ? CIN : 1], ishl[NORM_IN ? CIN : 1];
    __shared__ float lsum[PARTIALS ? 4 : 1][PARTIALS ? 64 : 1];
    __shared__ float lsq[PARTIALS ? 4 : 1][PARTIALS ? 64 : 1];
    for (int i = threadIdx.x; i < CIN * 64; i += 256) {
        int c = i >> 6, o = i & 63;
        wlds[i] = w[(ob + o) * CIN + c];
    }
    if (threadIdx.x < 64) blds[threadIdx.x] = bias[ob + threadIdx.x];
    if (NORM_IN) {
        for (int i = threadIdx.x; i < CIN; i += 256) { iscl[i] = isc[i]; ishl[i] = ish[i]; }
    }
    __syncthreads();
    int r = blockIdx.x * 256 + threadIdx.x;
    float acc[64];
#pragma unroll
    for (int o = 0; o < 64; ++o) acc[o] = blds[o];
    const float4* r4 = (const float4*)(Yin + (size_t)r * CIN);
#pragma unroll 4
    for (int cc = 0; cc < CIN / 4; ++cc) {
        float4 x = r4[cc];
        float xs[4] = {x.x, x.y, x.z, x.w};
#pragma unroll
        for (int u = 0; u < 4; ++u) {
            int c = cc * 4 + u;
            float xv = xs[u];
            if (NORM_IN) xv = fmaxf(fmaf(xv, iscl[c], ishl[c]), 0.0f);
            const float* wr = &wlds[c * 64];
#pragma unroll
            for (int o = 0; o < 64; ++o) acc[o] = fmaf(xv, wr[o], acc[o]);
        }
    }
    if (WRITE_Y) {
        float4* yr = (float4*)(Yout + (size_t)r * OTOT + ob);
#pragma unroll
        for (int o4 = 0; o4 < 16; ++o4)
            yr[o4] = make_float4(acc[o4 * 4], acc[o4 * 4 + 1], acc[o4 * 4 + 2], acc[o4 * 4 + 3]);
    }
    if (PARTIALS) {
        int lane = threadIdx.x & 63, wvv = threadIdx.x >> 6;
#pragma unroll
        for (int o = 0; o < 64; ++o) {
            float v = acc[o], v2 = acc[o] * acc[o];
#pragma unroll
            for (int off = 1; off < 64; off <<= 1) { v += __shfl_xor(v, off); v2 += __shfl_xor(v2, off); }
            if (lane == 0) { lsum[wvv][o] = v; lsq[wvv][o] = v2; }
        }
        __syncthreads();
        if (threadIdx.x < 64) {
            int o = threadIdx.x;
            sumP[blockIdx.x * OTOT + ob + o] = lsum[0][o] + lsum[1][o] + lsum[2][o] + lsum[3][o];
            sqP[blockIdx.x * OTOT + ob + o]  = lsq[0][o] + lsq[1][o] + lsq[2][o] + lsq[3][o];
        }
    }
    if (MAXOUT) {
        int b = r >> 15, s = (r >> 5) & (SS - 1);
#pragma unroll
        for (int o = 0; o < 64; ++o) {
            float v = acc[o];
#pragma unroll
            for (int off = 1; off < 32; off <<= 1) v = fmaxf(v, __shfl_xor(v, off));
            if ((threadIdx.x & 31) == 0)
                ymax[((size_t)b * O3 + ob + o) * SS + s] = v;
        }
    }
}

// ---------------- pool epilogue: out1 = relu(ymax*sc + sh), coalesced ----------
__global__ __launch_bounds__(256) void k_pool(const float* __restrict__ ymax,
                                              const float* __restrict__ sc,
                                              const float* __restrict__ sh,
                                              float* __restrict__ out1) {
    int i = blockIdx.x * 256 + threadIdx.x;    // over BB*O3*SS, layout == out1
    int o = (i >> 10) & (O3 - 1);              // wave-uniform channel
    out1[i] = fmaxf(fmaf(ymax[i], sc[o], sh[o]), 0.0f);
}

// ---------------- finalize BN stats: 512 partials -> scale/shift ---------------
template <int COUT>
__global__ void k_finalize(const float* __restrict__ sumP, const float* __restrict__ sqP,
                           const float* __restrict__ g, const float* __restrict__ beta,
                           float* __restrict__ scale, float* __restrict__ shift) {
    __shared__ float ls[4][COUT], lq[4][COUT];
    int o = threadIdx.x % COUT, q = threadIdx.x / COUT;
    float s = 0.f, qq = 0.f;
    for (int bk = q; bk < 512; bk += 4) { s += sumP[bk * COUT + o]; qq += sqP[bk * COUT + o]; }
    ls[q][o] = s; lq[q][o] = qq;
    __syncthreads();
    if (q == 0) {
        s  = ls[0][o] + ls[1][o] + ls[2][o] + ls[3][o];
        qq = lq[0][o] + lq[1][o] + lq[2][o] + lq[3][o];
        const float inv = 1.0f / (float)RR;
        float mean = s * inv;
        float var = qq * inv - mean * mean;
        float sc = g[o] * rsqrtf(var + EPSF);
        scale[o] = sc;
        shift[o] = beta[o] - mean * sc;
    }
}

extern "C" void kernel_launch(void* const* d_in, const int* in_sizes, int n_in,
                              void* d_out, int out_size, void* d_ws, size_t ws_size,
                              hipStream_t stream) {
    const float* xyz = (const float*)d_in[0];
    const float* pts = (const float*)d_in[1];
    const float* w1  = (const float*)d_in[2];
    const float* b1  = (const float*)d_in[3];
    const float* g1  = (const float*)d_in[4];
    const float* bt1 = (const float*)d_in[5];
    const float* w2  = (const float*)d_in[6];
    const float* b2  = (const float*)d_in[7];
    const float* g2  = (const float*)d_in[8];
    const float* bt2 = (const float*)d_in[9];
    const float* w3  = (const float*)d_in[10];
    const float* b3  = (const float*)d_in[11];
    const float* g3  = (const float*)d_in[12];
    const float* bt3 = (const float*)d_in[13];
    float* out0 = (float*)d_out;                 // (B,3,S)
    float* out1 = out0 + BB * 3 * SS;            // (B,128,S)

    char* wsb = (char*)d_ws;
    size_t off = 0;
    auto alloc = [&](size_t bytes) {
        char* p = wsb + off;
        off += (bytes + 255) & ~(size_t)255;
        return p;
    };
    int*   fps_idx = (int*)alloc((size_t)BB * SS * 4);
    int*   ballidx = (int*)alloc((size_t)RR * 4);
    float* nxyz    = (float*)alloc((size_t)BB * SS * 3 * 4);
    float* sumP    = (float*)alloc((size_t)512 * 128 * 4);
    float* sqP     = (float*)alloc((size_t)512 * 128 * 4);
    float* sc1     = (float*)alloc(128 * 4);
    float* sh1     = (float*)alloc(128 * 4);
    float* sc2     = (float*)alloc(128 * 4);
    float* sh2     = (float*)alloc(128 * 4);
    float* sc3     = (float*)alloc(128 * 4);
    float* sh3     = (float*)alloc(128 * 4);
    float* ymax    = (float*)alloc((size_t)BB * O3 * SS * 4);
    float* Y1      = (float*)alloc((size_t)RR * 64 * 4);
    float* Y2      = (float*)alloc((size_t)RR * 64 * 4);
    float* ptsT    = Y2;   // ptsT (16 MB) lives in Y2's slot; Y2 written after gemm1

    k_tr<<<1024, 256, 0, stream>>>(pts, ptsT);
    k_fps<<<BB, FT, 0, stream>>>(xyz, fps_idx);
    k_newxyz<<<16, 256, 0, stream>>>(xyz, fps_idx, out0, nxyz);
    k_ball<<<1024, 256, 0, stream>>>(xyz, nxyz, ballidx);

    k_gemm1<<<512, 256, 0, stream>>>(xyz, ptsT, nxyz, ballidx, w1, b1, Y1, sumP, sqP);
    k_finalize<64><<<1, 256, 0, stream>>>(sumP, sqP, g1, bt1, sc1, sh1);

    k_mlp<64, 64, true, true, true, false><<<dim3(512, 1), 256, 0, stream>>>(
        Y1, w2, b2, sc1, sh1, Y2, sumP, sqP, nullptr);
    k_finalize<64><<<1, 256, 0, stream>>>(sumP, sqP, g2, bt2, sc2, sh2);

    k_mlp<64, 128, true, false, true, true><<<dim3(512, 2), 256, 0, stream>>>(
        Y2, w3, b3, sc2, sh2, nullptr, sumP, sqP, ymax);
    k_finalize<128><<<1, 512, 0, stream>>>(sumP, sqP, g3, bt3, sc3, sh3);

    k_pool<<<BB * O3 * SS / 256, 256, 0, stream>>>(ymax, sc3, sh3, out1);
}